// Round 3
// baseline (165.310 us; speedup 1.0000x reference)
//
#include <hip/hip_runtime.h>
#include <float.h>

#define BATCH 64
#define NROWS 8192
#define NCH   64
#define SCHNK 16                 // N-chunks per batch
#define ROWS  (NROWS / SCHNK)    // 512 rows per block
#define TOPK  9

// ws layout: [B][SCHNK][TOPK][NCH] floats, then 64 int counters
#define PART_FLOATS ((size_t)BATCH * SCHNK * TOPK * NCH)   // 589824
#define CNT_BYTES   (BATCH * sizeof(int))                  // 256

// Insert v into descending-sorted m[0..8], keep top-9.
// r[0] = max(m[0], v); r[k] = median(m[k-1], m[k], v)  -- all depth-1, 9 ops.
__device__ __forceinline__ void insert9(float (&m)[TOPK], float v) {
    const float r0 = fmaxf(m[0], v);
#pragma unroll
    for (int k = TOPK - 1; k >= 1; --k)
        m[k] = __builtin_amdgcn_fmed3f(m[k - 1], m[k], v);
    m[0] = r0;
}

// Fused: each block streams its (batch, chunk), block-merges to a partial
// top-9 per channel, writes it to ws; the 16th-arriving block per batch
// merges the 16 partials and writes the mean to out.
__global__ __launch_bounds__(256) void topk_fused(const float* __restrict__ x,
                                                  float* __restrict__ ws,
                                                  int* __restrict__ cnt,
                                                  float* __restrict__ out) {
    const int bx = blockIdx.x;
    const int b  = bx >> 4;
    const int s  = bx & (SCHNK - 1);
    const int t  = threadIdx.x;
    const int cg = t & 15;
    const int ns = t >> 4;
    const int c  = t & 63;
    const int q  = t >> 6;

    float m[4][TOPK];
#pragma unroll
    for (int ch = 0; ch < 4; ++ch)
#pragma unroll
        for (int k = 0; k < TOPK; ++k) m[ch][k] = -FLT_MAX;

    // Stream: thread owns 4 channels (float4) x 32 rows; wave reads 1 KiB contig.
    const float4* xr = (const float4*)(x + ((size_t)b * NROWS + (size_t)s * ROWS) * NCH);
#pragma unroll 8
    for (int k = 0; k < ROWS / 16; ++k) {
        const float4 v = xr[ns * 16 + k * 256 + cg];
        insert9(m[0], v.x);
        insert9(m[1], v.y);
        insert9(m[2], v.z);
        insert9(m[3], v.w);
    }

    __shared__ float lists[16][NCH][TOPK];   // 36 KB (quarts aliased into rows 0,4,8,12)
#pragma unroll
    for (int ch = 0; ch < 4; ++ch)
#pragma unroll
        for (int k = 0; k < TOPK; ++k)
            lists[ns][4 * cg + ch][k] = m[ch][k];
    __syncthreads();

    // Stage A: wave q merges rows 4q..4q+3 -> row 4q (reads precede writes
    // within the lockstep wave; rows are wave-disjoint, so aliasing is safe).
    {
        float mm[TOPK];
#pragma unroll
        for (int k = 0; k < TOPK; ++k) mm[k] = lists[q * 4][c][k];
#pragma unroll
        for (int i = 1; i < 4; ++i)
#pragma unroll
            for (int k = 0; k < TOPK; ++k)
                insert9(mm, lists[q * 4 + i][c][k]);
#pragma unroll
        for (int k = 0; k < TOPK; ++k) lists[q * 4][c][k] = mm[k];
    }
    __syncthreads();

    // Stage B: 64 threads merge rows 0,4,8,12; write partial to ws.
    if (t < NCH) {
        float mm[TOPK];
#pragma unroll
        for (int k = 0; k < TOPK; ++k) mm[k] = lists[0][t][k];
#pragma unroll
        for (int qq = 1; qq < 4; ++qq)
#pragma unroll
            for (int k = 0; k < TOPK; ++k)
                insert9(mm, lists[qq * 4][t][k]);
        float* w = ws + ((size_t)(b * SCHNK + s) * TOPK) * NCH;
#pragma unroll
        for (int k = 0; k < TOPK; ++k) w[k * NCH + t] = mm[k];
    }

    // Release partials, count arrivals; last block per batch does the final.
    __threadfence();
    __shared__ int lastFlag;
    __syncthreads();                 // writers' fences complete before the atomic
    if (t == 0) lastFlag = (atomicAdd(&cnt[b], 1) == SCHNK - 1);
    __syncthreads();
    if (!lastFlag) return;
    __threadfence();                 // acquire: see peers' partials

    // Final merge for batch b: stage A over 16 lists (4 per wave)...
    const float* w = ws + (size_t)b * SCHNK * TOPK * NCH;
    {
        float mm[TOPK];
#pragma unroll
        for (int k = 0; k < TOPK; ++k) mm[k] = w[((q * 4) * TOPK + k) * NCH + c];
#pragma unroll
        for (int i = 1; i < 4; ++i)
#pragma unroll
            for (int k = 0; k < TOPK; ++k)
                insert9(mm, w[((q * 4 + i) * TOPK + k) * NCH + c]);
#pragma unroll
        for (int k = 0; k < TOPK; ++k) lists[q][c][k] = mm[k];
    }
    __syncthreads();
    // ...then stage B: merge 4 quarter-lists, mean, store.
    if (t < NCH) {
        float r[TOPK];
#pragma unroll
        for (int k = 0; k < TOPK; ++k) r[k] = lists[0][t][k];
#pragma unroll
        for (int q2 = 1; q2 < 4; ++q2)
#pragma unroll
            for (int k = 0; k < TOPK; ++k)
                insert9(r, lists[q2][t][k]);
        float sum = 0.f;
#pragma unroll
        for (int k = 0; k < TOPK; ++k) sum += r[k];
        out[b * NCH + t] = sum * (1.0f / 9.0f);
    }
}

extern "C" void kernel_launch(void* const* d_in, const int* in_sizes, int n_in,
                              void* d_out, int out_size, void* d_ws, size_t ws_size,
                              hipStream_t stream) {
    const float* x = (const float*)d_in[0];
    float* out = (float*)d_out;
    float* ws  = (float*)d_ws;                 // partials: 2.25 MiB
    int*   cnt = (int*)(ws + PART_FLOATS);     // 64 counters after partials

    hipMemsetAsync(cnt, 0, CNT_BYTES, stream); // deterministic counter init
    topk_fused<<<BATCH * SCHNK, 256, 0, stream>>>(x, ws, cnt, out);
}

// Round 4
// 30.775 us; speedup vs baseline: 5.3715x; 5.3715x over previous
//
#include <hip/hip_runtime.h>
#include <float.h>

#define BATCH 64
#define NROWS 8192
#define NCH   64
#define SCHNK 16                 // N-chunks per batch
#define ROWS  (NROWS / SCHNK)    // 512 rows per block
#define TOPK  9

// Insert v into descending-sorted m[0..8], keep top-9.
// r[0] = max(m[0], v); r[k] = median(m[k-1], m[k], v)  -- all depth-1, 9 ops.
__device__ __forceinline__ void insert9(float (&m)[TOPK], float v) {
    const float r0 = fmaxf(m[0], v);
#pragma unroll
    for (int k = TOPK - 1; k >= 1; --k)
        m[k] = __builtin_amdgcn_fmed3f(m[k - 1], m[k], v);
    m[0] = r0;
}

// Kernel 1: per-(batch,chunk) block: top-9 per channel over its 512 rows.
// 36 KB LDS (stage-A results aliased into lists rows 0,4,8,12) -> 4 blocks/CU,
// so all 1024 blocks are co-resident: one full-BW round, no tail.
__global__ __launch_bounds__(256) void topk_partial(const float* __restrict__ x,
                                                    float* __restrict__ ws) {
    const int bx = blockIdx.x;
    const int b  = bx >> 4;
    const int s  = bx & (SCHNK - 1);
    const int t  = threadIdx.x;
    const int cg = t & 15;
    const int ns = t >> 4;
    const int c  = t & 63;
    const int q  = t >> 6;

    float m[4][TOPK];
#pragma unroll
    for (int ch = 0; ch < 4; ++ch)
#pragma unroll
        for (int k = 0; k < TOPK; ++k) m[ch][k] = -FLT_MAX;

    // Stream: thread owns 4 channels (float4) x 32 rows; wave reads 1 KiB contig.
    const float4* xr = (const float4*)(x + ((size_t)b * NROWS + (size_t)s * ROWS) * NCH);
#pragma unroll 8
    for (int k = 0; k < ROWS / 16; ++k) {
        const float4 v = xr[ns * 16 + k * 256 + cg];
        insert9(m[0], v.x);
        insert9(m[1], v.y);
        insert9(m[2], v.z);
        insert9(m[3], v.w);
    }

    __shared__ float lists[16][NCH][TOPK];   // 36 KB; stage-A merges in place
#pragma unroll
    for (int ch = 0; ch < 4; ++ch)
#pragma unroll
        for (int k = 0; k < TOPK; ++k)
            lists[ns][4 * cg + ch][k] = m[ch][k];
    __syncthreads();

    // Stage A: wave q merges rows 4q..4q+3 -> row 4q. Rows are wave-disjoint;
    // all reads precede the write-back in program order, so aliasing is safe.
    {
        float mm[TOPK];
#pragma unroll
        for (int k = 0; k < TOPK; ++k) mm[k] = lists[q * 4][c][k];
#pragma unroll
        for (int i = 1; i < 4; ++i)
#pragma unroll
            for (int k = 0; k < TOPK; ++k)
                insert9(mm, lists[q * 4 + i][c][k]);
#pragma unroll
        for (int k = 0; k < TOPK; ++k) lists[q * 4][c][k] = mm[k];
    }
    __syncthreads();

    // Stage B: 64 threads merge rows 0,4,8,12; write partial to ws.
    if (t < NCH) {
        float mm[TOPK];
#pragma unroll
        for (int k = 0; k < TOPK; ++k) mm[k] = lists[0][t][k];
#pragma unroll
        for (int qq = 1; qq < 4; ++qq)
#pragma unroll
            for (int k = 0; k < TOPK; ++k)
                insert9(mm, lists[qq * 4][t][k]);
        // ws layout: [B][SCHNK][TOPK][NCH] (coalesced across channel lanes)
        float* w = ws + ((size_t)(b * SCHNK + s) * TOPK) * NCH;
#pragma unroll
        for (int k = 0; k < TOPK; ++k) w[k * NCH + t] = mm[k];
    }
}

// Kernel 2: merge SCHNK partial lists per (b,c); mean of final top-9.
__global__ __launch_bounds__(256) void topk_final(const float* __restrict__ ws,
                                                  float* __restrict__ out) {
    const int b = blockIdx.x;
    const int t = threadIdx.x;
    const int c = t & 63;
    const int q = t >> 6;
    __shared__ float quarts[4][NCH][TOPK];   // 9 KB

    const float* w = ws + (size_t)b * SCHNK * TOPK * NCH;
    float mm[TOPK];
#pragma unroll
    for (int k = 0; k < TOPK; ++k) mm[k] = w[((q * 4) * TOPK + k) * NCH + c];
#pragma unroll
    for (int i = 1; i < 4; ++i)
#pragma unroll
        for (int k = 0; k < TOPK; ++k)
            insert9(mm, w[((q * 4 + i) * TOPK + k) * NCH + c]);
#pragma unroll
    for (int k = 0; k < TOPK; ++k) quarts[q][c][k] = mm[k];
    __syncthreads();

    if (t < NCH) {
        float r[TOPK];
#pragma unroll
        for (int k = 0; k < TOPK; ++k) r[k] = quarts[0][t][k];
#pragma unroll
        for (int q2 = 1; q2 < 4; ++q2)
#pragma unroll
            for (int k = 0; k < TOPK; ++k)
                insert9(r, quarts[q2][t][k]);
        float sum = 0.f;
#pragma unroll
        for (int k = 0; k < TOPK; ++k) sum += r[k];
        out[b * NCH + t] = sum * (1.0f / 9.0f);
    }
}

extern "C" void kernel_launch(void* const* d_in, const int* in_sizes, int n_in,
                              void* d_out, int out_size, void* d_ws, size_t ws_size,
                              hipStream_t stream) {
    const float* x = (const float*)d_in[0];
    float* out = (float*)d_out;
    float* ws = (float*)d_ws;   // needs B*S*9*C*4 = 2.25 MiB

    topk_partial<<<BATCH * SCHNK, 256, 0, stream>>>(x, ws);
    topk_final<<<BATCH, 256, 0, stream>>>(ws, out);
}